// Round 7
// baseline (66.315 us; speedup 1.0000x reference)
//
#include <hip/hip_runtime.h>
#include <math.h>

#define KCOMP 32
#define DDIM 64
#define LOG_2PI 1.8378770664093453f

#define WROW 128                      // f16 per swizzled W row (16 chunks x 8)
#define WBYTES (DDIM * WROW * 2)      // 16384 B per component

typedef _Float16 half8 __attribute__((ext_vector_type(8)));
typedef float floatx16 __attribute__((ext_vector_type(16)));

__device__ inline void gload_lds16(const void* g, void* l) {
    __builtin_amdgcn_global_load_lds(
        (const __attribute__((address_space(1))) void*)g,
        (__attribute__((address_space(3))) void*)l, 16, 0, 0);
}

__device__ inline float rdlane(float v, int l) {
    return __uint_as_float(__builtin_amdgcn_readlane(__float_as_uint(v), l));
}

// ---------------------------------------------------------------------------
// Prep: register-resident Cholesky + triangular inverse, one wave/component.
// Row t of Sigma/L lives in lane t's VGPRs; ALL broadcasts via v_readlane
// (constant lane index -> SGPR, no LDS/ds_bpermute on the critical path).
// grid = KCOMP blocks x 64 threads.
// ---------------------------------------------------------------------------
__global__ __launch_bounds__(64, 1) void gmm_prep(const float* __restrict__ loc,
                                                  const float* __restrict__ cov,
                                                  const float* __restrict__ pi,
                                                  _Float16* __restrict__ wt,
                                                  float* __restrict__ cstout)
{
    const int k = blockIdx.x;
    const int t = threadIdx.x;

    __shared__ float M[DDIM][DDIM + 1];
    __shared__ float mu_s[DDIM];

    float Srow[DDIM];   // Sigma row t
    float Lrow[DDIM];   // L row t
    float Mcol[DDIM];   // M column t

    {
        const float4* Sg = (const float4*)(cov + (size_t)k * DDIM * DDIM + (size_t)t * DDIM);
        #pragma unroll
        for (int q = 0; q < DDIM / 4; ++q) {
            float4 v = Sg[q];
            Srow[q * 4 + 0] = v.x; Srow[q * 4 + 1] = v.y;
            Srow[q * 4 + 2] = v.z; Srow[q * 4 + 3] = v.w;
        }
    }
    mu_s[t] = loc[k * DDIM + t];

    // ---- left-looking Cholesky, rows in registers ----
    float hld = 0.f;   // uniform: 0.5 * sum log d_j
    #pragma unroll
    for (int j = 0; j < DDIM; ++j) {
        float a0 = 0.f, a1 = 0.f, a2 = 0.f, a3 = 0.f;
        #pragma unroll
        for (int c = 0; c < j; ++c) {
            float ljc = rdlane(Lrow[c], j);      // L[j][c], SGPR broadcast
            switch (c & 3) {
                case 0: a0 += Lrow[c] * ljc; break;
                case 1: a1 += Lrow[c] * ljc; break;
                case 2: a2 += Lrow[c] * ljc; break;
                default: a3 += Lrow[c] * ljc; break;
            }
        }
        float v = Srow[j] - ((a0 + a1) + (a2 + a3));
        float dj = rdlane(v, j);                 // diagonal d_j (pre-sqrt)
        float r = rsqrtf(dj);
        r = r * (1.5f - 0.5f * dj * r * r);      // one Newton step
        Lrow[j] = (t >= j) ? v * r : 0.f;
        hld += 0.5f * logf(dj);
    }

    // ---- M = L^{-1}: lane t builds column t, row-sequential ----
    #pragma unroll
    for (int i = 0; i < DDIM; ++i) {
        float a0 = 0.f, a1 = 0.f, a2 = 0.f, a3 = 0.f;
        #pragma unroll
        for (int c = 0; c < i; ++c) {
            float lic = rdlane(Lrow[c], i);      // L[i][c]
            switch (c & 3) {
                case 0: a0 += lic * Mcol[c]; break;
                case 1: a1 += lic * Mcol[c]; break;
                case 2: a2 += lic * Mcol[c]; break;
                default: a3 += lic * Mcol[c]; break;
            }
        }
        float dinv = 1.0f / rdlane(Lrow[i], i);  // uniform
        float s = (a0 + a1) + (a2 + a3);
        Mcol[i] = (t < i) ? (-s * dinv) : ((t == i) ? dinv : 0.f);
    }

    // flush M columns -> LDS rows (one time)
    #pragma unroll
    for (int i = 0; i < DDIM; ++i) M[i][t] = Mcol[i];
    __syncthreads();

    // ---- b_t = sum_j M[t][j] * mu[j] (upper of M is zero) ----
    float bt = 0.f;
    #pragma unroll 4
    for (int j = 0; j < DDIM; ++j) bt += M[t][j] * mu_s[j];

    // ---- emit swizzled f16 row t of W~ ----
    // swizzle key g = row & 7: within a 16-lane ds_read_b128 group (16
    // consecutive rows, same chunk c) the chunk positions c^g cover all 8
    // bank groups exactly twice -> 2-way (free).
    _Float16* wrow = wt + (size_t)k * DDIM * WROW + (size_t)t * WROW;
    const int g = t & 7;

    #pragma unroll
    for (int c = 0; c < 8; ++c) {          // data chunks: M row
        half8 v;
        #pragma unroll
        for (int e = 0; e < 8; ++e) v[e] = (_Float16)M[t][c * 8 + e];
        *(half8*)(wrow + (size_t)(c ^ g) * 8) = v;
    }
    {   // chunk 8: -b split hi/lo (pairs with x~=1,1)
        float nb = -bt;
        _Float16 h0 = (_Float16)nb;
        _Float16 h1 = (_Float16)(nb - (float)h0);
        half8 v;
        #pragma unroll
        for (int e = 0; e < 8; ++e) v[e] = (_Float16)0.f;
        v[0] = h0; v[1] = h1;
        *(half8*)(wrow + (size_t)(8 ^ g) * 8) = v;
    }
    #pragma unroll
    for (int c = 9; c < 16; ++c) {         // zero padding chunks
        half8 v;
        #pragma unroll
        for (int e = 0; e < 8; ++e) v[e] = (_Float16)0.f;
        *(half8*)(wrow + (size_t)(c ^ g) * 8) = v;
    }

    if (t == 0) {
        float mxp = pi[0];
        for (int i = 1; i < KCOMP; ++i) mxp = fmaxf(mxp, pi[i]);
        float s = 0.f;
        for (int i = 0; i < KCOMP; ++i) s += __expf(pi[i] - mxp);
        float lse = mxp + logf(s);
        cstout[k] = (pi[k] - lse) - hld - 0.5f * (float)DDIM * LOG_2PI;
    }
}

// ---------------------------------------------------------------------------
// Main: MFMA z = W~ x~. 256 threads = 4 waves x 64 points each (2 B-frag
// groups/wave) -> per-CU LDS read traffic HALVED vs 32 pts/wave (A-fragment
// reads amortize over 2x points), staging traffic halved (256 blocks).
// 2 components staged per iteration (2 x 32 KB LDS buffers), 16 barrier
// intervals, 8 independent accumulators for MFMA ILP at 1 wave/SIMD.
// ---------------------------------------------------------------------------
__global__ __launch_bounds__(256, 1) void gmm_main(const float* __restrict__ X,
                                                   const _Float16* __restrict__ wt,
                                                   const float* __restrict__ cst,
                                                   float* __restrict__ out)
{
    __shared__ char wbuf[2][2 * WBYTES];      // 64 KB

    const int tid  = threadIdx.x;
    const int wave = tid >> 6;
    const int lane = tid & 63;
    const int col  = lane & 31;
    const int h    = lane >> 5;
    const int bid  = blockIdx.x;
    const int ptbase = bid * 256 + wave * 64;   // this wave's 64 points
    const int rot  = (bid * 2) & 31;            // even rotation keeps pairs intact

    // issue stage of first component pair into buf 0 (8 KB per wave)
    {
        const char* gsrc = (const char*)wt + (size_t)rot * WBYTES;
        #pragma unroll
        for (int j = 0; j < 8; ++j) {
            int off = wave * 8192 + j * 1024;
            gload_lds16(gsrc + off + lane * 16, &wbuf[0][off]);
        }
    }

    // build B fragments (x~) for both 32-point groups, overlapping the stage
    half8 bf0[5], bf1[5];
    #pragma unroll
    for (int grp = 0; grp < 2; ++grp) {
        const float* xr = X + (size_t)(ptbase + grp * 32 + col) * DDIM;
        half8* bf = grp ? bf1 : bf0;
        #pragma unroll
        for (int s = 0; s < 4; ++s) {
            int c = s * 2 + h;
            float4 lo = *(const float4*)(xr + c * 8);
            float4 hi = *(const float4*)(xr + c * 8 + 4);
            half8 v;
            v[0] = (_Float16)lo.x; v[1] = (_Float16)lo.y;
            v[2] = (_Float16)lo.z; v[3] = (_Float16)lo.w;
            v[4] = (_Float16)hi.x; v[5] = (_Float16)hi.y;
            v[6] = (_Float16)hi.z; v[7] = (_Float16)hi.w;
            bf[s] = v;
        }
        half8 v;
        #pragma unroll
        for (int e = 0; e < 8; ++e) v[e] = (_Float16)0.f;
        if (h == 0) { v[0] = (_Float16)1.f; v[1] = (_Float16)1.f; }
        bf[4] = v;   // augmented slice: pairs with (-b_hi, -b_lo)
    }

    float mx0 = -INFINITY, sm0 = 0.f;   // group 0 LSE state
    float mx1 = -INFINITY, sm1 = 0.f;   // group 1 LSE state

    __syncthreads();   // emits vmcnt(0) drain: stage 0 complete

    const int g0 = col & 7;   // swizzle key (rows col and col+32 share it)
    int cur = 0;

    #pragma unroll 1
    for (int kk = 0; kk < KCOMP / 2; ++kk) {
        const int cb = (2 * kk + rot) & 31;        // even; pair = cb, cb+1
        // prefetch next pair into the other buffer (32 KB contiguous)
        if (kk + 1 < KCOMP / 2) {
            const int cbn = (2 * kk + 2 + rot) & 31;
            const char* gsrc = (const char*)wt + (size_t)cbn * WBYTES;
            #pragma unroll
            for (int j = 0; j < 8; ++j) {
                int off = wave * 8192 + j * 1024;
                gload_lds16(gsrc + off + lane * 16, &wbuf[cur ^ 1][off]);
            }
        }

        // acc naming: [p|q] = comp cb / cb+1, [A|B] = point group 0/1,
        // [0|1] = row tile (rows 0-31 / 32-63)
        floatx16 pA0 = {0.f}, pA1 = {0.f}, pB0 = {0.f}, pB1 = {0.f};
        floatx16 qA0 = {0.f}, qA1 = {0.f}, qB0 = {0.f}, qB1 = {0.f};
        const char* wb0 = wbuf[cur];
        const char* wb1 = wbuf[cur] + WBYTES;

        #pragma unroll
        for (int s = 0; s < 5; ++s) {
            int c = 2 * s + h;
            int p = c ^ g0;
            half8 WA0 = *(const half8*)(wb0 + (size_t)col * 256 + p * 16);
            half8 WA1 = *(const half8*)(wb0 + (size_t)(col + 32) * 256 + p * 16);
            half8 WB0 = *(const half8*)(wb1 + (size_t)col * 256 + p * 16);
            half8 WB1 = *(const half8*)(wb1 + (size_t)(col + 32) * 256 + p * 16);
            pA0 = __builtin_amdgcn_mfma_f32_32x32x16_f16(WA0, bf0[s], pA0, 0, 0, 0);
            pA1 = __builtin_amdgcn_mfma_f32_32x32x16_f16(WA1, bf0[s], pA1, 0, 0, 0);
            pB0 = __builtin_amdgcn_mfma_f32_32x32x16_f16(WA0, bf1[s], pB0, 0, 0, 0);
            pB1 = __builtin_amdgcn_mfma_f32_32x32x16_f16(WA1, bf1[s], pB1, 0, 0, 0);
            qA0 = __builtin_amdgcn_mfma_f32_32x32x16_f16(WB0, bf0[s], qA0, 0, 0, 0);
            qA1 = __builtin_amdgcn_mfma_f32_32x32x16_f16(WB1, bf0[s], qA1, 0, 0, 0);
            qB0 = __builtin_amdgcn_mfma_f32_32x32x16_f16(WB0, bf1[s], qB0, 0, 0, 0);
            qB1 = __builtin_amdgcn_mfma_f32_32x32x16_f16(WB1, bf1[s], qB1, 0, 0, 0);
        }

        // maha = sum_i z_i^2 per (comp, group): per-lane partial + pair swap
        float sP0 = 0.f, sP1 = 0.f, sQ0 = 0.f, sQ1 = 0.f;
        #pragma unroll
        for (int r = 0; r < 16; ++r) {
            sP0 += pA0[r] * pA0[r] + pA1[r] * pA1[r];
            sP1 += pB0[r] * pB0[r] + pB1[r] * pB1[r];
            sQ0 += qA0[r] * qA0[r] + qA1[r] * qA1[r];
            sQ1 += qB0[r] * qB0[r] + qB1[r] * qB1[r];
        }
        sP0 += __shfl_xor(sP0, 32);
        sP1 += __shfl_xor(sP1, 32);
        sQ0 += __shfl_xor(sQ0, 32);
        sQ1 += __shfl_xor(sQ1, 32);

        float c0 = cst[cb], c1 = cst[cb + 1];
        float lpP0 = c0 - 0.5f * sP0;
        float lpQ0 = c1 - 0.5f * sQ0;
        float nm0 = fmaxf(mx0, fmaxf(lpP0, lpQ0));
        sm0 = sm0 * __expf(mx0 - nm0) + __expf(lpP0 - nm0) + __expf(lpQ0 - nm0);
        mx0 = nm0;

        float lpP1 = c0 - 0.5f * sP1;
        float lpQ1 = c1 - 0.5f * sQ1;
        float nm1 = fmaxf(mx1, fmaxf(lpP1, lpQ1));
        sm1 = sm1 * __expf(mx1 - nm1) + __expf(lpP1 - nm1) + __expf(lpQ1 - nm1);
        mx1 = nm1;

        __syncthreads();   // drains vmcnt (prefetch done) + protects buffers
        cur ^= 1;
    }

    if (h == 0) {
        out[ptbase + col]      = mx0 + logf(sm0);
        out[ptbase + 32 + col] = mx1 + logf(sm1);
    }
}

// ---------------------------------------------------------------------------
extern "C" void kernel_launch(void* const* d_in, const int* in_sizes, int n_in,
                              void* d_out, int out_size, void* d_ws, size_t ws_size,
                              hipStream_t stream) {
    const float* X   = (const float*)d_in[0];
    const float* loc = (const float*)d_in[1];
    const float* cov = (const float*)d_in[2];
    const float* pi  = (const float*)d_in[3];
    float* out = (float*)d_out;

    char* ws = (char*)d_ws;
    _Float16* wt = (_Float16*)ws;                                   // 512 KB
    float* cstp  = (float*)(ws + (size_t)KCOMP * DDIM * WROW * 2);  // 128 B

    const int n = in_sizes[0] / DDIM;   // 65536

    gmm_prep<<<KCOMP, 64, 0, stream>>>(loc, cov, pi, wt, cstp);
    gmm_main<<<n / 256, 256, 0, stream>>>(X, wt, cstp, out);
}

// Round 8
// 59.973 us; speedup vs baseline: 1.1057x; 1.1057x over previous
//
#include <hip/hip_runtime.h>
#include <math.h>

#define KCOMP 32
#define DDIM 64
#define LOG_2PI 1.8378770664093453f

// W~ fragment-major layout: frag index f = (comp*2 + r)*5 + s, each frag is
// 1024 B = 64 lanes x 16 B (one half8 per lane). Per comp: 10 frags = 10240 B.
#define WFRAG_HALF8S 64
#define WCOMP_BYTES 10240

typedef _Float16 half8 __attribute__((ext_vector_type(8)));
typedef float floatx16 __attribute__((ext_vector_type(16)));

__device__ inline float rdlane(float v, int l) {
    return __uint_as_float(__builtin_amdgcn_readlane(__float_as_uint(v), l));
}

// ---------------------------------------------------------------------------
// Prep: register-resident Cholesky + triangular inverse, one wave/component.
// Row t of Sigma/L lives in lane t's VGPRs; broadcasts via v_readlane.
// Emits W~ = (M | -b_hi,-b_lo | 0) in FRAGMENT-MAJOR f16 layout so the main
// kernel's A-fragment load is one coalesced 1 KB global_load_dwordx4.
// grid = KCOMP blocks x 64 threads.
// ---------------------------------------------------------------------------
__global__ __launch_bounds__(64, 1) void gmm_prep(const float* __restrict__ loc,
                                                  const float* __restrict__ cov,
                                                  const float* __restrict__ pi,
                                                  _Float16* __restrict__ wt,
                                                  float* __restrict__ cstout)
{
    const int k = blockIdx.x;
    const int t = threadIdx.x;

    __shared__ float M[DDIM][DDIM + 1];
    __shared__ float mu_s[DDIM];

    float Srow[DDIM];   // Sigma row t
    float Lrow[DDIM];   // L row t
    float Mcol[DDIM];   // M column t

    {
        const float4* Sg = (const float4*)(cov + (size_t)k * DDIM * DDIM + (size_t)t * DDIM);
        #pragma unroll
        for (int q = 0; q < DDIM / 4; ++q) {
            float4 v = Sg[q];
            Srow[q * 4 + 0] = v.x; Srow[q * 4 + 1] = v.y;
            Srow[q * 4 + 2] = v.z; Srow[q * 4 + 3] = v.w;
        }
    }
    mu_s[t] = loc[k * DDIM + t];

    // ---- left-looking Cholesky, rows in registers ----
    float hld = 0.f;   // uniform: 0.5 * sum log d_j
    #pragma unroll
    for (int j = 0; j < DDIM; ++j) {
        float a0 = 0.f, a1 = 0.f, a2 = 0.f, a3 = 0.f;
        #pragma unroll
        for (int c = 0; c < j; ++c) {
            float ljc = rdlane(Lrow[c], j);      // L[j][c], SGPR broadcast
            switch (c & 3) {
                case 0: a0 += Lrow[c] * ljc; break;
                case 1: a1 += Lrow[c] * ljc; break;
                case 2: a2 += Lrow[c] * ljc; break;
                default: a3 += Lrow[c] * ljc; break;
            }
        }
        float v = Srow[j] - ((a0 + a1) + (a2 + a3));
        float dj = rdlane(v, j);                 // diagonal d_j (pre-sqrt)
        float r = rsqrtf(dj);
        r = r * (1.5f - 0.5f * dj * r * r);      // one Newton step
        Lrow[j] = (t >= j) ? v * r : 0.f;
        hld += 0.5f * logf(dj);
    }

    // ---- M = L^{-1}: lane t builds column t, row-sequential ----
    #pragma unroll
    for (int i = 0; i < DDIM; ++i) {
        float a0 = 0.f, a1 = 0.f, a2 = 0.f, a3 = 0.f;
        #pragma unroll
        for (int c = 0; c < i; ++c) {
            float lic = rdlane(Lrow[c], i);      // L[i][c]
            switch (c & 3) {
                case 0: a0 += lic * Mcol[c]; break;
                case 1: a1 += lic * Mcol[c]; break;
                case 2: a2 += lic * Mcol[c]; break;
                default: a3 += lic * Mcol[c]; break;
            }
        }
        float dinv = 1.0f / rdlane(Lrow[i], i);  // uniform
        float s = (a0 + a1) + (a2 + a3);
        Mcol[i] = (t < i) ? (-s * dinv) : ((t == i) ? dinv : 0.f);
    }

    // flush M columns -> LDS rows (one time)
    #pragma unroll
    for (int i = 0; i < DDIM; ++i) M[i][t] = Mcol[i];
    __syncthreads();

    // ---- b_t = sum_j M[t][j] * mu[j] (upper of M is zero) ----
    float bt = 0.f;
    #pragma unroll 4
    for (int j = 0; j < DDIM; ++j) bt += M[t][j] * mu_s[j];

    // ---- emit fragment-major f16 W~: thread t = z-row t ----
    // A-frag for mfma_32x32x16_f16: lane l holds A[l&31][(l>>5)*8 + e].
    // Row t, feature chunk c (8 halves) -> frag s = c>>1, frag-lane
    // fl = (t&31) + 32*(c&1), tile r = t>>5.
    {
        const int r = t >> 5, lrow = t & 31;
        half8* wp = (half8*)wt;
        const size_t fbase = ((size_t)k * 2 + r) * 5;   // frag index base
        #pragma unroll
        for (int c = 0; c < 8; ++c) {          // data chunks: M row
            half8 v;
            #pragma unroll
            for (int e = 0; e < 8; ++e) v[e] = (_Float16)M[t][c * 8 + e];
            int fl = lrow + 32 * (c & 1);
            wp[(fbase + (c >> 1)) * WFRAG_HALF8S + fl] = v;
        }
        {   // chunk 8 (s=4, fl=lrow): -b split hi/lo (pairs with x~=1,1)
            float nb = -bt;
            _Float16 h0 = (_Float16)nb;
            _Float16 h1 = (_Float16)(nb - (float)h0);
            half8 v;
            #pragma unroll
            for (int e = 0; e < 8; ++e) v[e] = (_Float16)0.f;
            v[0] = h0; v[1] = h1;
            wp[(fbase + 4) * WFRAG_HALF8S + lrow] = v;
        }
        {   // chunk 9 (s=4, fl=lrow+32): zeros
            half8 v;
            #pragma unroll
            for (int e = 0; e < 8; ++e) v[e] = (_Float16)0.f;
            wp[(fbase + 4) * WFRAG_HALF8S + lrow + 32] = v;
        }
    }

    if (t == 0) {
        float mxp = pi[0];
        for (int i = 1; i < KCOMP; ++i) mxp = fmaxf(mxp, pi[i]);
        float s = 0.f;
        for (int i = 0; i < KCOMP; ++i) s += __expf(pi[i] - mxp);
        float lse = mxp + logf(s);
        cstout[k] = (pi[k] - lse) - hld - 0.5f * (float)DDIM * LOG_2PI;
    }
}

// ---------------------------------------------------------------------------
// Main: NO LDS staging, no hot-loop barriers. Block = 4 waves = 4 component
// slices (8 comps each) over the SAME 128 points. X-frags in registers;
// W~ fragments stream L2 -> regs (coalesced 1 KB loads), double-buffered
// wfA (tile 0) / wfB (tile 1). Slices merge via 4 KB LDS + one barrier.
// grid = 512 blocks x 256 threads -> 8 waves/CU = 2/SIMD.
// ---------------------------------------------------------------------------
__global__ __launch_bounds__(256, 1) void gmm_main(const float* __restrict__ X,
                                                   const _Float16* __restrict__ wt,
                                                   const float* __restrict__ cst,
                                                   float* __restrict__ out)
{
    __shared__ float2 part[4][128];       // [slice][point] partial (mx, sm)

    const int tid  = threadIdx.x;
    const int wave = tid >> 6;            // = component slice
    const int lane = tid & 63;
    const int col  = lane & 31;
    const int h    = lane >> 5;
    const int ptbase = blockIdx.x * 128;

    // ---- build B fragments (x~) for 4 point-groups of 32 ----
    half8 bf[4][5];
    #pragma unroll
    for (int g = 0; g < 4; ++g) {
        const float* xr = X + (size_t)(ptbase + g * 32 + col) * DDIM;
        #pragma unroll
        for (int s = 0; s < 4; ++s) {
            int c = s * 2 + h;
            float4 lo = *(const float4*)(xr + c * 8);
            float4 hi = *(const float4*)(xr + c * 8 + 4);
            half8 v;
            v[0] = (_Float16)lo.x; v[1] = (_Float16)lo.y;
            v[2] = (_Float16)lo.z; v[3] = (_Float16)lo.w;
            v[4] = (_Float16)hi.x; v[5] = (_Float16)hi.y;
            v[6] = (_Float16)hi.z; v[7] = (_Float16)hi.w;
            bf[g][s] = v;
        }
        half8 v;
        #pragma unroll
        for (int e = 0; e < 8; ++e) v[e] = (_Float16)0.f;
        if (h == 0) { v[0] = (_Float16)1.f; v[1] = (_Float16)1.f; }
        bf[g][4] = v;   // augmented slice: pairs with (-b_hi, -b_lo)
    }

    const half8* wp = (const half8*)wt;
    const int comp0 = wave * 8;

    float mx[4], sm[4];
    #pragma unroll
    for (int g = 0; g < 4; ++g) { mx[g] = -INFINITY; sm[g] = 0.f; }

    half8 wfA[5], wfB[5];
    // preload tile-0 frags of first comp
    #pragma unroll
    for (int s = 0; s < 5; ++s)
        wfA[s] = wp[((size_t)comp0 * 2 + 0) * 5 * WFRAG_HALF8S + s * WFRAG_HALF8S + lane];

    #pragma unroll 1
    for (int q = 0; q < 8; ++q) {
        const int c = comp0 + q;

        // issue tile-1 frag loads (overlap with tile-0 MFMA below)
        #pragma unroll
        for (int s = 0; s < 5; ++s)
            wfB[s] = wp[((size_t)c * 2 + 1) * 5 * WFRAG_HALF8S + s * WFRAG_HALF8S + lane];

        float sP[4];

        {   // tile 0: z-rows 0..31
            floatx16 a0 = {0.f}, a1 = {0.f}, a2 = {0.f}, a3 = {0.f};
            #pragma unroll
            for (int s = 0; s < 5; ++s) {
                a0 = __builtin_amdgcn_mfma_f32_32x32x16_f16(wfA[s], bf[0][s], a0, 0, 0, 0);
                a1 = __builtin_amdgcn_mfma_f32_32x32x16_f16(wfA[s], bf[1][s], a1, 0, 0, 0);
                a2 = __builtin_amdgcn_mfma_f32_32x32x16_f16(wfA[s], bf[2][s], a2, 0, 0, 0);
                a3 = __builtin_amdgcn_mfma_f32_32x32x16_f16(wfA[s], bf[3][s], a3, 0, 0, 0);
            }
            float p0 = 0.f, p1 = 0.f, p2 = 0.f, p3 = 0.f;
            #pragma unroll
            for (int r = 0; r < 16; ++r) {
                p0 += a0[r] * a0[r]; p1 += a1[r] * a1[r];
                p2 += a2[r] * a2[r]; p3 += a3[r] * a3[r];
            }
            sP[0] = p0; sP[1] = p1; sP[2] = p2; sP[3] = p3;
        }

        // issue next comp's tile-0 loads (overlap with tile-1 MFMA below)
        if (q < 7) {
            #pragma unroll
            for (int s = 0; s < 5; ++s)
                wfA[s] = wp[((size_t)(c + 1) * 2 + 0) * 5 * WFRAG_HALF8S + s * WFRAG_HALF8S + lane];
        }

        {   // tile 1: z-rows 32..63
            floatx16 a0 = {0.f}, a1 = {0.f}, a2 = {0.f}, a3 = {0.f};
            #pragma unroll
            for (int s = 0; s < 5; ++s) {
                a0 = __builtin_amdgcn_mfma_f32_32x32x16_f16(wfB[s], bf[0][s], a0, 0, 0, 0);
                a1 = __builtin_amdgcn_mfma_f32_32x32x16_f16(wfB[s], bf[1][s], a1, 0, 0, 0);
                a2 = __builtin_amdgcn_mfma_f32_32x32x16_f16(wfB[s], bf[2][s], a2, 0, 0, 0);
                a3 = __builtin_amdgcn_mfma_f32_32x32x16_f16(wfB[s], bf[3][s], a3, 0, 0, 0);
            }
            float p0 = 0.f, p1 = 0.f, p2 = 0.f, p3 = 0.f;
            #pragma unroll
            for (int r = 0; r < 16; ++r) {
                p0 += a0[r] * a0[r]; p1 += a1[r] * a1[r];
                p2 += a2[r] * a2[r]; p3 += a3[r] * a3[r];
            }
            sP[0] += p0; sP[1] += p1; sP[2] += p2; sP[3] += p3;
        }

        const float ck = cst[c];
        #pragma unroll
        for (int g = 0; g < 4; ++g) {
            float sfull = sP[g] + __shfl_xor(sP[g], 32);
            float lp = ck - 0.5f * sfull;
            float nm = fmaxf(mx[g], lp);
            sm[g] = sm[g] * __expf(mx[g] - nm) + __expf(lp - nm);
            mx[g] = nm;
        }
    }

    // ---- merge the 4 slices in-block ----
    if (h == 0) {
        #pragma unroll
        for (int g = 0; g < 4; ++g)
            part[wave][g * 32 + col] = make_float2(mx[g], sm[g]);
    }
    __syncthreads();

    if (tid < 128) {
        float2 p0 = part[0][tid], p1 = part[1][tid];
        float2 p2 = part[2][tid], p3 = part[3][tid];
        float m = fmaxf(fmaxf(p0.x, p1.x), fmaxf(p2.x, p3.x));
        float s = p0.y * __expf(p0.x - m) + p1.y * __expf(p1.x - m)
                + p2.y * __expf(p2.x - m) + p3.y * __expf(p3.x - m);
        out[ptbase + tid] = m + logf(s);
    }
}

// ---------------------------------------------------------------------------
extern "C" void kernel_launch(void* const* d_in, const int* in_sizes, int n_in,
                              void* d_out, int out_size, void* d_ws, size_t ws_size,
                              hipStream_t stream) {
    const float* X   = (const float*)d_in[0];
    const float* loc = (const float*)d_in[1];
    const float* cov = (const float*)d_in[2];
    const float* pi  = (const float*)d_in[3];
    float* out = (float*)d_out;

    char* ws = (char*)d_ws;
    _Float16* wt = (_Float16*)ws;                              // 320 KB
    float* cstp  = (float*)(ws + (size_t)KCOMP * WCOMP_BYTES); // 128 B

    const int n = in_sizes[0] / DDIM;   // 65536

    gmm_prep<<<KCOMP, 64, 0, stream>>>(loc, cov, pi, wt, cstp);
    gmm_main<<<n / 128, 256, 0, stream>>>(X, wt, cstp, out);
}